// Round 6
// baseline (20.562 us; speedup 1.0000x reference)
//
#include <hip/hip_runtime.h>
#include <cmath>

// Problem constants (fixed by the reference)
#define B_ 256
#define I_ 1024
#define O_ 1024

typedef __attribute__((ext_vector_type(8))) short short8;   // 8 bf16 = 4 VGPRs
typedef __attribute__((ext_vector_type(4))) float f32x4;

// float -> bf16 bits, round-to-nearest-even (inputs are finite after clamp)
__device__ inline unsigned short f2bf(float f) {
  union { float f; unsigned u; } c;
  c.f = f;
  unsigned u = c.u;
  return (unsigned short)((u + 0x7FFFu + ((u >> 16) & 1u)) >> 16);
}

// fast log(tanh(100|x|)) = log(1-t) - log(1+t), t = e^{-200|x|}  (HW exp/log)
// x==0: log(0) = -inf -> clamped to -1e30; exp(sum) = 0 downstream. ✓
// large |x|: t underflows to 0 -> lt = 0. ✓
__device__ inline float fast_lt(float xv) {
  float z = 100.0f * fabsf(xv);
  float t = __expf(-2.0f * z);
  float lt = __logf(1.0f - t) - __logf(1.0f + t);
  return fmaxf(lt, -1e30f);
}

// ---------------------------------------------------------------------------
// Single fused kernel: inline fp32->bf16 prep + dual MFMA GEMM + epilogue.
// Tile 32(M) x 32(N); 512 threads = 8 waves; intra-block split-K:
// wave-group kg = wid>>2 covers K-half [kg*512,+512) in 8 iters of BK=64.
// Each thread loads 6 float4 (x, vw, fcw), converts in-register to
// (x_bf16, logtanh_bf16, fc*mask_bf16, mask_bf16), stages to LDS (144B rows,
// conflict-free for both b128 stores and fragment reads), MFMAs 2x per ks.
// Cross-group combine: 8KB LDS reduce + fused exp/relu epilogue.
// XCD-chunked remap: each XCD (bid&7) owns a 4Mx8N tile rectangle ->
// ~2.5MB unique/XCD, re-reads are L2-hits.
// No workspace, no second kernel.
// ---------------------------------------------------------------------------
__global__ __launch_bounds__(512) void harsanyi_fused(
    const float* __restrict__ x, const float* __restrict__ vw,
    const float* __restrict__ fcw, float* __restrict__ out) {
  const int bid = blockIdx.x;
  const int cx = bid & 7, wi = bid >> 3;       // chunk (=XCD), index within
  const int nblk = (cx & 3) * 8 + (wi & 7);    // 0..31
  const int mblk = (cx >> 2) * 4 + (wi >> 3);  // 0..7
  const int on0 = nblk * 32, bm0 = mblk * 32;

  __shared__ short As[2][32][72];
  __shared__ short Ls[2][32][72];
  __shared__ short Ws[2][32][72];
  __shared__ short Ms[2][32][72];

  const int t = threadIdx.x;
  const int lane = t & 63;
  const int wid = t >> 6;            // 0..7
  const int kg = wid >> 2;           // K-group (0: k<512, 1: k>=512)
  const int wm = (wid >> 1) & 1, wn = wid & 1;
  const int lr = lane & 15;
  const int lk = (lane >> 4) * 8;

  const int tl = t & 255;            // thread index within group
  const int srow = tl >> 3;          // staging row 0..31
  const int scol = (tl & 7) * 8;     // staging col (elems)

  const float* xp = x + (size_t)(bm0 + srow) * I_ + kg * 512 + scol;
  const float* vp = vw + (size_t)(on0 + srow) * I_ + kg * 512 + scol;
  const float* fp = fcw + (size_t)(on0 + srow) * I_ + kg * 512 + scol;

  // load tile 0 (6 x float4 per thread)
  float4 xa0 = *(const float4*)(xp);
  float4 xa1 = *(const float4*)(xp + 4);
  float4 va0 = *(const float4*)(vp);
  float4 va1 = *(const float4*)(vp + 4);
  float4 fa0 = *(const float4*)(fp);
  float4 fa1 = *(const float4*)(fp + 4);

  f32x4 accd = {0.f, 0.f, 0.f, 0.f};
  f32x4 accs = {0.f, 0.f, 0.f, 0.f};

  for (int kt = 0; kt < 512; kt += 64) {
    // convert current tile in-register (loads had the prev MFMA phase to land)
    float xa[8] = {xa0.x, xa0.y, xa0.z, xa0.w, xa1.x, xa1.y, xa1.z, xa1.w};
    float va[8] = {va0.x, va0.y, va0.z, va0.w, va1.x, va1.y, va1.z, va1.w};
    float fa[8] = {fa0.x, fa0.y, fa0.z, fa0.w, fa1.x, fa1.y, fa1.z, fa1.w};
    short8 xs_, ls_, ws_, ms_;
#pragma unroll
    for (int j = 0; j < 8; ++j) {
      xs_[j] = (short)f2bf(xa[j]);
      ls_[j] = (short)f2bf(fast_lt(xa[j]));
      bool m = va[j] > 0.0f;
      ws_[j] = m ? (short)f2bf(fa[j]) : (short)0;
      ms_[j] = (short)(m ? 0x3F80 : 0x0000);  // bf16 1.0 / 0.0
    }
    __syncthreads();  // previous iter's LDS reads done before overwrite
    *(short8*)(&As[kg][srow][scol]) = xs_;
    *(short8*)(&Ls[kg][srow][scol]) = ls_;
    *(short8*)(&Ws[kg][srow][scol]) = ws_;
    *(short8*)(&Ms[kg][srow][scol]) = ms_;
    if (kt + 64 < 512) {  // issue next-tile loads; latency hides under MFMA
      xa0 = *(const float4*)(xp + kt + 64);
      xa1 = *(const float4*)(xp + kt + 68);
      va0 = *(const float4*)(vp + kt + 64);
      va1 = *(const float4*)(vp + kt + 68);
      fa0 = *(const float4*)(fp + kt + 64);
      fa1 = *(const float4*)(fp + kt + 68);
    }
    __syncthreads();
#pragma unroll
    for (int ks = 0; ks < 2; ++ks) {
      const int kb = ks * 32 + lk;
      short8 af = *(const short8*)(&As[kg][wm * 16 + lr][kb]);
      short8 lf = *(const short8*)(&Ls[kg][wm * 16 + lr][kb]);
      short8 wf = *(const short8*)(&Ws[kg][wn * 16 + lr][kb]);
      short8 mf = *(const short8*)(&Ms[kg][wn * 16 + lr][kb]);
      accd = __builtin_amdgcn_mfma_f32_16x16x32_bf16(af, wf, accd, 0, 0, 0);
      accs = __builtin_amdgcn_mfma_f32_16x16x32_bf16(lf, mf, accs, 0, 0, 0);
    }
  }

  // Cross-group reduce (group 1 -> LDS, group 0 adds) + fused epilogue.
  __syncthreads();
  float* red = (float*)(&As[0][0][0]);  // 8KB needed, 9216B available
  const int ridx = ((wid & 3) * 64 + lane) * 8;
  if (kg == 1) {
#pragma unroll
    for (int r = 0; r < 4; ++r) {
      red[ridx + r] = accd[r];
      red[ridx + 4 + r] = accs[r];
    }
  }
  __syncthreads();
  if (kg == 0) {
    // C/D layout: col = lane&15, row = (lane>>4)*4 + reg   [m89-verified]
    const int orow = bm0 + wm * 16 + (lane >> 4) * 4;
    const int ocol = on0 + wn * 16 + lr;
#pragma unroll
    for (int r = 0; r < 4; ++r) {
      float dsum = accd[r] + red[ridx + r];
      float ssum = accs[r] + red[ridx + 4 + r];
      float d = __expf(ssum);
      float y = fmaxf(dsum * d, 0.0f);
      size_t off = (size_t)(orow + r) * O_ + ocol;
      out[off] = y;
      out[(size_t)B_ * O_ + off] = d;
    }
  }
}

extern "C" void kernel_launch(void* const* d_in, const int* in_sizes, int n_in,
                              void* d_out, int out_size, void* d_ws,
                              size_t ws_size, hipStream_t stream) {
  const float* x = (const float*)d_in[0];
  const float* vw = (const float*)d_in[1];
  const float* fcw = (const float*)d_in[2];
  float* out = (float*)d_out;

  harsanyi_fused<<<256, 512, 0, stream>>>(x, vw, fcw, out);
}